// Round 1
// baseline (735.854 us; speedup 1.0000x reference)
//
#include <hip/hip_runtime.h>
#include <hip/hip_bf16.h>
#include <cstdint>
#include <cstddef>

#define NH   16
#define DHD  64
#define DM   1024
#define BSZ  8
#define SEQ  4096
#define NTOK (BSZ*SEQ)      // 32768 tokens
#define NQKV (3*NH*DHD)     // 3072

typedef __attribute__((ext_vector_type(8))) __bf16 bf16x8;
typedef __attribute__((ext_vector_type(4))) float  floatx4;

// ---- helpers ----
static __device__ __forceinline__ unsigned short f2bf(float f) {
    unsigned int u = __float_as_uint(f);
    u += 0x7fffu + ((u >> 16) & 1u);   // RNE
    return (unsigned short)(u >> 16);
}
static __device__ __forceinline__ float bf2f(unsigned int us) {
    return __uint_as_float(us << 16);
}
static __device__ __forceinline__ void load_lds16(const void* g, void* l) {
    __builtin_amdgcn_global_load_lds((__attribute__((address_space(1))) void*)g,
                                     (__attribute__((address_space(3))) void*)l,
                                     16, 0, 0);
}

// ---- cast fp32 -> bf16 (vectorized, exact multiple of 4) ----
__global__ __launch_bounds__(256) void k_cast_bf16(const float* __restrict__ in,
                                                   unsigned short* __restrict__ out, int n4) {
    int i = blockIdx.x * 256 + threadIdx.x;
    if (i >= n4) return;
    float4 v = ((const float4*)in)[i];
    ushort4 o;
    o.x = f2bf(v.x); o.y = f2bf(v.y); o.z = f2bf(v.z); o.w = f2bf(v.w);
    ((ushort4*)out)[i] = o;
}

// ---- transpose + cast: in fp32 [R][C] -> out bf16 [C][R] ----
template<int R, int C>
__global__ __launch_bounds__(256) void k_transpose_cast(const float* __restrict__ in,
                                                        unsigned short* __restrict__ out) {
    __shared__ float tile[32][33];
    int tx = threadIdx.x, ty = threadIdx.y;    // (32, 8)
    int col = blockIdx.x * 32 + tx;
#pragma unroll
    for (int k = 0; k < 4; k++) {
        int row = blockIdx.y * 32 + ty + k * 8;
        tile[ty + k * 8][tx] = in[(size_t)row * C + col];
    }
    __syncthreads();
#pragma unroll
    for (int k = 0; k < 4; k++) {
        int ocol = blockIdx.x * 32 + ty + k * 8;   // original col -> out row
        int orow = blockIdx.y * 32 + tx;           // original row -> out col
        out[(size_t)ocol * R + orow] = f2bf(tile[tx][ty + k * 8]);
    }
}

// ---- positional encoding table fp32 [4096][64] ----
__global__ __launch_bounds__(256) void k_pe(float* __restrict__ pe) {
    int t = blockIdx.x * 256 + threadIdx.x;   // 4096*32
    int l = t >> 5, i = t & 31;
    // div_term = exp(2i * (-ln(10000)/64))
    float dv = expf(-0.14391156831212787f * (float)(2 * i));
    float ang = (float)l * dv;
    pe[l * 64 + 2 * i]     = sinf(ang);
    pe[l * 64 + 2 * i + 1] = cosf(ang);
}

// ---- m97-style bf16 GEMM: C[M][N] = A[M][1024] @ BT[N][1024]^T + bias ----
// EPI==1: qkv epilogue (q *= 0.125, k += pe, store bf16); EPI==0: store fp32
template<int N, int EPI>
__global__ __launch_bounds__(256) void k_gemm(const unsigned short* __restrict__ A,
                                              const unsigned short* __restrict__ BT,
                                              const float* __restrict__ bias,
                                              const float* __restrict__ pe,
                                              void* __restrict__ Cout) {
    constexpr int K = 1024;
    __shared__ __align__(16) short lds[8192];   // As[128][32] + Bs[128][32] bf16
    short* As = lds;
    short* Bs = lds + 4096;

    int tid  = threadIdx.x;
    int lane = tid & 63;
    int wid  = tid >> 6;
    int m0 = blockIdx.y * 128;
    int n0 = blockIdx.x * 128;
    int wr = wid >> 1, wc = wid & 1;
    int l15 = lane & 15;
    int kq  = (lane >> 4) * 8;

    floatx4 acc[4][4];
#pragma unroll
    for (int i = 0; i < 4; i++)
#pragma unroll
        for (int j = 0; j < 4; j++) acc[i][j] = (floatx4){0.f, 0.f, 0.f, 0.f};

    // staging: 512 16B-chunks per 8KB buffer; wave w covers chunks [w*128, w*128+128)
    int ci0 = wid * 128 + lane;
    int ci1 = ci0 + 64;
    const unsigned short* pa0 = A  + (size_t)(m0 + (ci0 >> 2)) * K + (ci0 & 3) * 8;
    const unsigned short* pa1 = A  + (size_t)(m0 + (ci1 >> 2)) * K + (ci1 & 3) * 8;
    const unsigned short* pb0 = BT + (size_t)(n0 + (ci0 >> 2)) * K + (ci0 & 3) * 8;
    const unsigned short* pb1 = BT + (size_t)(n0 + (ci1 >> 2)) * K + (ci1 & 3) * 8;
    short* la0 = As + ci0 * 8;
    short* la1 = As + ci1 * 8;
    short* lb0 = Bs + ci0 * 8;
    short* lb1 = Bs + ci1 * 8;

    for (int kb = 0; kb < K; kb += 32) {
        __syncthreads();                       // previous compute done
        load_lds16(pa0 + kb, la0);
        load_lds16(pa1 + kb, la1);
        load_lds16(pb0 + kb, lb0);
        load_lds16(pb1 + kb, lb1);
        __syncthreads();                       // staging visible (vmcnt drain)

        bf16x8 aF[4], bF[4];
#pragma unroll
        for (int i = 0; i < 4; i++)
            aF[i] = *(const bf16x8*)&As[(wr * 64 + i * 16 + l15) * 32 + kq];
#pragma unroll
        for (int j = 0; j < 4; j++)
            bF[j] = *(const bf16x8*)&Bs[(wc * 64 + j * 16 + l15) * 32 + kq];
#pragma unroll
        for (int i = 0; i < 4; i++)
#pragma unroll
            for (int j = 0; j < 4; j++)
                acc[i][j] = __builtin_amdgcn_mfma_f32_16x16x32_bf16(aF[i], bF[j], acc[i][j], 0, 0, 0);
    }

    int rbase = (lane >> 4) * 4;
#pragma unroll
    for (int j = 0; j < 4; j++) {
        int col = n0 + wc * 64 + j * 16 + l15;
        float bv = bias[col];
        int h = 0, rc = 0;
        if (EPI == 1) { h = col / 192; rc = col - h * 192; }
#pragma unroll
        for (int i = 0; i < 4; i++) {
#pragma unroll
            for (int r = 0; r < 4; r++) {
                int row = m0 + wr * 64 + i * 16 + rbase + r;
                float v = acc[i][j][r] + bv;
                if (EPI == 1) {
                    if (rc < 64)        v *= 0.125f;                       // q pre-scale (1/sqrt(64))
                    else if (rc < 128)  v += pe[(row & (SEQ - 1)) * 64 + (rc - 64)]; // k + pos_enc
                    ((unsigned short*)Cout)[(size_t)row * N + col] = f2bf(v);
                } else {
                    ((float*)Cout)[(size_t)row * N + col] = v;
                }
            }
        }
    }
}

// ---- per-token across-heads attention: 1 wave per token ----
// qkv row layout: head h -> [q(64) | k(64) | v(64)] at col h*192; q pre-scaled, k has pe.
__global__ __launch_bounds__(256) void k_attn(const unsigned short* __restrict__ qkv,
                                              unsigned short* __restrict__ aout) {
    __shared__ __align__(16) float X4[4][3264];   // per-wave: 16 rows, stride 204 (bank-friendly)
    __shared__ float S4[4][272];                  // softmax probs, [16][17]
    int tid = threadIdx.x, wid = tid >> 6, lane = tid & 63;
    int t = blockIdx.x * 4 + wid;

    float* X = X4[wid];
    const unsigned short* src = qkv + (size_t)t * NQKV;

    // load 3072 bf16 -> fp32 LDS (6 x 16B chunks per lane)
#pragma unroll
    for (int c = 0; c < 6; c++) {
        int ci = c * 64 + lane;
        uint4 u = ((const uint4*)src)[ci];
        int j0 = ci * 8;
        int h  = j0 / 192;
        int rc = j0 - h * 192;
        float* dst = X + h * 204 + rc;
        floatx4 f0 = { bf2f(u.x & 0xffff), bf2f(u.x >> 16), bf2f(u.y & 0xffff), bf2f(u.y >> 16) };
        floatx4 f1 = { bf2f(u.z & 0xffff), bf2f(u.z >> 16), bf2f(u.w & 0xffff), bf2f(u.w >> 16) };
        *(floatx4*)dst       = f0;
        *(floatx4*)(dst + 4) = f1;
    }
    __syncthreads();

    // scores: lane = (h, 4 g's). S[h][g] = q_h . k_g  (q already /8)
    int h  = lane >> 2;
    int g0 = (lane & 3) * 4;
    const float* Q = X + h * 204;
    float s0 = 0.f, s1 = 0.f, s2 = 0.f, s3 = 0.f;
#pragma unroll 8
    for (int d = 0; d < 64; d++) {
        float qd = Q[d];
        s0 += qd * X[(g0 + 0) * 204 + 64 + d];
        s1 += qd * X[(g0 + 1) * 204 + 64 + d];
        s2 += qd * X[(g0 + 2) * 204 + 64 + d];
        s3 += qd * X[(g0 + 3) * 204 + 64 + d];
    }
    // softmax over g (row h lives in 4 lanes; reduce via shfl_xor 1,2)
    float mx = fmaxf(fmaxf(s0, s1), fmaxf(s2, s3));
    mx = fmaxf(mx, __shfl_xor(mx, 1));
    mx = fmaxf(mx, __shfl_xor(mx, 2));
    float e0 = __expf(s0 - mx), e1 = __expf(s1 - mx), e2 = __expf(s2 - mx), e3 = __expf(s3 - mx);
    float sum = e0 + e1 + e2 + e3;
    sum += __shfl_xor(sum, 1);
    sum += __shfl_xor(sum, 2);
    float inv = 1.0f / sum;
    float* Sr = &S4[wid][h * 17];
    Sr[g0 + 0] = e0 * inv; Sr[g0 + 1] = e1 * inv; Sr[g0 + 2] = e2 * inv; Sr[g0 + 3] = e3 * inv;
    __syncthreads();

    // O[h][d] = sum_g p[h][g] * v[g][d]; lane = (h, db), d = db*16 + 0..15
    int db = lane & 3;
    floatx4 o0 = {0,0,0,0}, o1 = {0,0,0,0}, o2 = {0,0,0,0}, o3 = {0,0,0,0};
    const float* Sh = &S4[wid][h * 17];
#pragma unroll
    for (int g = 0; g < 16; g++) {
        float p = Sh[g];
        const floatx4* Vg = (const floatx4*)(X + g * 204 + 128 + db * 16);
        o0 += Vg[0] * p;
        o1 += Vg[1] * p;
        o2 += Vg[2] * p;
        o3 += Vg[3] * p;
    }
    // store 16 contiguous bf16 at col h*64 + db*16
    unsigned int w[8];
    w[0] = (unsigned)f2bf(o0[0]) | ((unsigned)f2bf(o0[1]) << 16);
    w[1] = (unsigned)f2bf(o0[2]) | ((unsigned)f2bf(o0[3]) << 16);
    w[2] = (unsigned)f2bf(o1[0]) | ((unsigned)f2bf(o1[1]) << 16);
    w[3] = (unsigned)f2bf(o1[2]) | ((unsigned)f2bf(o1[3]) << 16);
    w[4] = (unsigned)f2bf(o2[0]) | ((unsigned)f2bf(o2[1]) << 16);
    w[5] = (unsigned)f2bf(o2[2]) | ((unsigned)f2bf(o2[3]) << 16);
    w[6] = (unsigned)f2bf(o3[0]) | ((unsigned)f2bf(o3[1]) << 16);
    w[7] = (unsigned)f2bf(o3[2]) | ((unsigned)f2bf(o3[3]) << 16);
    uint4* dst = (uint4*)&aout[(size_t)t * DM + h * 64 + db * 16];
    dst[0] = make_uint4(w[0], w[1], w[2], w[3]);
    dst[1] = make_uint4(w[4], w[5], w[6], w[7]);
}

extern "C" void kernel_launch(void* const* d_in, const int* in_sizes, int n_in,
                              void* d_out, int out_size, void* d_ws, size_t ws_size,
                              hipStream_t stream) {
    const float* x     = (const float*)d_in[0];
    const float* w_qkv = (const float*)d_in[1];
    const float* b_qkv = (const float*)d_in[2];
    const float* w_out = (const float*)d_in[3];
    const float* b_out = (const float*)d_in[4];
    float* out = (float*)d_out;

    // ws layout (bytes):
    //   pe      fp32 [4096][64]        @ 0          (1 MiB)
    //   wqkvT   bf16 [3072][1024]      @ 1 MiB      (6 MiB)
    //   woutT   bf16 [1024][1024]      @ 7 MiB      (2 MiB)
    //   xbf     bf16 [32768][1024]     @ 9 MiB      (64 MiB)   (reused as attn_out)
    //   qkv     bf16 [32768][3072]     @ 73 MiB     (192 MiB)
    char* ws = (char*)d_ws;
    float*          pe    = (float*)ws;
    unsigned short* wqkvT = (unsigned short*)(ws + (1u << 20));
    unsigned short* woutT = (unsigned short*)(ws + (1u << 20) + 6291456u);
    unsigned short* xbf   = (unsigned short*)(ws + (1u << 20) + 6291456u + 2097152u);
    unsigned short* qkv   = (unsigned short*)(ws + (1u << 20) + 6291456u + 2097152u + 67108864u);
    unsigned short* aout  = xbf;  // x_bf16 dead after GEMM1; reuse for attention output

    // prep
    k_cast_bf16<<<(NTOK * DM / 4 + 255) / 256, 256, 0, stream>>>(x, xbf, NTOK * DM / 4);
    k_transpose_cast<1024, 3072><<<dim3(96, 32), dim3(32, 8), 0, stream>>>(w_qkv, wqkvT);
    k_transpose_cast<1024, 1024><<<dim3(32, 32), dim3(32, 8), 0, stream>>>(w_out, woutT);
    k_pe<<<512, 256, 0, stream>>>(pe);

    // qkv = x @ w_qkv + b_qkv  (fused: q*=1/8, k+=pe, bf16 store)
    k_gemm<NQKV, 1><<<dim3(NQKV / 128, NTOK / 128), 256, 0, stream>>>(xbf, wqkvT, b_qkv, pe, qkv);

    // per-token across-heads attention
    k_attn<<<NTOK / 4, 256, 0, stream>>>(qkv, aout);

    // out = attn_out @ w_out + b_out (fp32 store)
    k_gemm<DM, 0><<<dim3(DM / 128, NTOK / 128), 256, 0, stream>>>(aout, woutT, b_out, nullptr, out);
}